// Round 8
// baseline (555.814 us; speedup 1.0000x reference)
//
#include <hip/hip_runtime.h>
#include <hip/hip_bf16.h>

#define TTOK 8192
#define DDIM 512
#define HDIM 2048
#define NEXP 8
#define RBLK 256                 // router blocks
#define RTOK (TTOK / RBLK)       // 32 tokens per router block

typedef __bf16 bf16x8 __attribute__((ext_vector_type(8)));
typedef float f32x4 __attribute__((ext_vector_type(4)));
typedef unsigned short us8 __attribute__((ext_vector_type(8)));

__device__ __forceinline__ unsigned short f2bf(float f) {
  unsigned int u = __builtin_bit_cast(unsigned int, f);
  u += 0x7fffu + ((u >> 16) & 1u);
  return (unsigned short)(u >> 16);
}

// ---------------- router: logits, top-2, gates, per-block positions; fused x->bf16 ----------------
__global__ __launch_bounds__(256) void k_router(
    const float* __restrict__ x, const float* __restrict__ rw,
    const float* __restrict__ rb, float* __restrict__ logits,
    unsigned short* __restrict__ xb,
    short* __restrict__ texp, unsigned short* __restrict__ tpos,
    float* __restrict__ tgate, int* __restrict__ blockcnt) {
  __shared__ int lcnt[NEXP];
  const int tid = threadIdx.x, wid = tid >> 6, lane = tid & 63;
  if (tid < NEXP) lcnt[tid] = 0;
  __syncthreads();
  // hoist router weights: lane covers floats [lane*8, lane*8+8)
  float4 w0[NEXP], w1[NEXP];
  float rbv[NEXP];
#pragma unroll
  for (int e = 0; e < NEXP; ++e) {
    const float4* wp = (const float4*)(rw + e * DDIM);
    w0[e] = wp[lane * 2];
    w1[e] = wp[lane * 2 + 1];
    rbv[e] = rb[e];
  }
  const int tbase = blockIdx.x * RTOK;
  for (int it = 0; it < RTOK / 4; ++it) {
    const int t = tbase + it * 4 + wid;
    const float4* xr = (const float4*)(x + (size_t)t * DDIM);
    float4 v0 = xr[lane * 2], v1 = xr[lane * 2 + 1];
    // fused bf16 conversion (replaces a separate k_cvt_x pass)
    us8 o;
    o[0] = f2bf(v0.x); o[1] = f2bf(v0.y); o[2] = f2bf(v0.z); o[3] = f2bf(v0.w);
    o[4] = f2bf(v1.x); o[5] = f2bf(v1.y); o[6] = f2bf(v1.z); o[7] = f2bf(v1.w);
    *(us8*)(xb + (size_t)t * DDIM + lane * 8) = o;
    float a[NEXP];
#pragma unroll
    for (int e = 0; e < NEXP; ++e)
      a[e] = v0.x * w0[e].x + v0.y * w0[e].y + v0.z * w0[e].z + v0.w * w0[e].w +
             v1.x * w1[e].x + v1.y * w1[e].y + v1.z * w1[e].z + v1.w * w1[e].w;
#pragma unroll
    for (int off = 32; off > 0; off >>= 1)
#pragma unroll
      for (int e = 0; e < NEXP; ++e) a[e] += __shfl_xor(a[e], off, 64);
    if (lane == 0) {
      float lg[NEXP];
#pragma unroll
      for (int e = 0; e < NEXP; ++e) lg[e] = a[e] + rbv[e];
      float4 s0, s1;
      s0.x = lg[0]; s0.y = lg[1]; s0.z = lg[2]; s0.w = lg[3];
      s1.x = lg[4]; s1.y = lg[5]; s1.z = lg[6]; s1.w = lg[7];
      ((float4*)(logits + t * NEXP))[0] = s0;
      ((float4*)(logits + t * NEXP))[1] = s1;
      int i0 = 0; float m0 = lg[0];
#pragma unroll
      for (int e = 1; e < NEXP; ++e) if (lg[e] > m0) { m0 = lg[e]; i0 = e; }
      int i1 = 0; float m1 = -3.4e38f;
#pragma unroll
      for (int e = 0; e < NEXP; ++e) if (e != i0 && lg[e] > m1) { m1 = lg[e]; i1 = e; }
      float e1 = expf(m1 - m0);
      float inv = 1.0f / (1.0f + e1);
      int p0 = atomicAdd(&lcnt[i0], 1);  // LDS atomic: block-local, cheap
      int p1 = atomicAdd(&lcnt[i1], 1);
      texp[t * 2] = (short)i0;     tpos[t * 2] = (unsigned short)p0;     tgate[t * 2] = inv;
      texp[t * 2 + 1] = (short)i1; tpos[t * 2 + 1] = (unsigned short)p1; tgate[t * 2 + 1] = e1 * inv;
    }
  }
  __syncthreads();
  if (tid < NEXP) blockcnt[blockIdx.x * NEXP + tid] = lcnt[tid];
}

// ---------------- per-block bases + expert counts/offsets (one wave) ----------------
__global__ void k_offsets(const int* __restrict__ blockcnt, int* __restrict__ blockbase,
                          int* __restrict__ counts, int* __restrict__ offsets) {
  const int e = threadIdx.x;
  if (e < NEXP) {
    int run = 0;
#pragma unroll 8
    for (int b = 0; b < RBLK; ++b) {
      blockbase[b * NEXP + e] = run;
      run += blockcnt[b * NEXP + e];
    }
    counts[e] = run;
  }
  __syncthreads();
  if (e == 0) {
    int s = 0;
    for (int q = 0; q < NEXP; ++q) { offsets[q] = s; s += counts[q]; }
  }
}

// ---------------- scatter: build packed per-expert token lists ----------------
// toklist/gates are per-expert segments (stride TTOK): position = blockbase+tpos ONLY.
__global__ void k_scatter(const short* __restrict__ texp, const unsigned short* __restrict__ tpos,
                          const float* __restrict__ tgate, const int* __restrict__ blockbase,
                          int* __restrict__ toklist, float* __restrict__ gates) {
  const int t = blockIdx.x * 256 + threadIdx.x;
  const int b = t / RTOK;
#pragma unroll
  for (int k = 0; k < 2; ++k) {
    const int e = (int)texp[t * 2 + k];
    const int pos = blockbase[b * NEXP + e] + (int)tpos[t * 2 + k];
    toklist[e * TTOK + pos] = t;
    gates[e * TTOK + pos] = tgate[t * 2 + k];
  }
}

// ---------------- fused weight transpose: w1 [E][D][H]->[E][H][D], w2 [E][H][D]->[E][D][H] ----------------
__global__ void k_transpose2(const float* __restrict__ w1, const float* __restrict__ w2,
                             unsigned short* __restrict__ w1t, unsigned short* __restrict__ w2t) {
  __shared__ float tile[32][33];
  const int id = blockIdx.x;
  const float* in; unsigned short* out; int R, C, rem;
  if (id < 8192) {  // w1: R=DDIM rows, C=HDIM cols
    const int e = id >> 10; rem = id & 1023;
    R = DDIM; C = HDIM;
    in = w1 + (size_t)e * R * C; out = w1t + (size_t)e * R * C;
  } else {          // w2: R=HDIM, C=DDIM
    const int e = (id - 8192) >> 10; rem = (id - 8192) & 1023;
    R = HDIM; C = DDIM;
    in = w2 + (size_t)e * R * C; out = w2t + (size_t)e * R * C;
  }
  const int ctiles = C >> 5;
  const int c0 = (rem % ctiles) * 32, r0 = (rem / ctiles) * 32;
  const int tx = threadIdx.x, ty = threadIdx.y;
#pragma unroll
  for (int i = 0; i < 32; i += 8)
    tile[ty + i][tx] = in[(size_t)(r0 + ty + i) * C + (c0 + tx)];
  __syncthreads();
#pragma unroll
  for (int i = 0; i < 32; i += 8)
    out[(size_t)(c0 + ty + i) * R + (r0 + tx)] = f2bf(tile[tx][ty + i]);
}

// ---------------- grouped GEMM, 32KB LDS, register-staged prefetch (T14) ----------------
// PHASE1: xb@w1 -> gelu -> h; PHASE2: h@w2 -> atomic scatter to out (split-K=2).
// 1D grid with expert in low 3 bits (round-robin wg->XCD => expert->XCD L2 affinity).
// K-loop: issue next tile's global loads into regs BEFORE current tile's MFMAs
// (latency hides under compute); post-MFMA barrier; ds_write regs; barrier.
template <int PHASE>
__global__ __launch_bounds__(256, 4) void k_gemm(
    const unsigned short* __restrict__ A, const unsigned short* __restrict__ Bt,
    const float* __restrict__ bias, const int* __restrict__ counts,
    const int* __restrict__ offsets, const int* __restrict__ toklist,
    const float* __restrict__ gates, unsigned short* __restrict__ Hout,
    float* __restrict__ Out) {
  constexpr int K = (PHASE == 1) ? DDIM : HDIM;   // reduction dim
  constexpr int NN = (PHASE == 1) ? HDIM : DDIM;  // output cols
  constexpr int KB = K * 2;                       // row bytes of A/Bt
  constexpr int NX = NN / 128;                    // n-tiles
  constexpr int NXSH = (PHASE == 1) ? 4 : 2;      // log2(NX)
  constexpr int SPLITK = (PHASE == 1) ? 1 : 2;    // phase2: 2x K-split for block parallelism
  constexpr int KCH = K / SPLITK;                 // K-chunk per block
  constexpr int NT = KCH / 64;                    // K-steps per block

  const int id = blockIdx.x;
  const int e = id & 7;
  int p = id >> 3;
  int s = 0;
  if (SPLITK > 1) { s = p & (SPLITK - 1); p >>= 1; }
  const int cnt = counts[e];
  const int m0 = (p >> NXSH) * 128;
  if (m0 >= cnt) return;
  const int n0 = (p & (NX - 1)) * 128;
  const int off = offsets[e];
  const int kbase = s * KCH * 2;  // byte offset along K

  __shared__ alignas(16) unsigned char smem[32768];  // A tile 16KB | B tile 16KB

  const int tid = threadIdx.x;
  const int wid = tid >> 6, lane = tid & 63;

  // staging: 16 chunks of 1KB per tile; chunk c covers rows [c*8, c*8+8), 128B/row.
  // LDS layout linear; global source byte-in-row pre-XOR-swizzled so the swizzled
  // ds_read below sees the right data (both-sides involution).
  const char* asrc[4];
  const char* bsrc[4];
  unsigned adst[4], bdst[4];
#pragma unroll
  for (int i = 0; i < 4; ++i) {
    const int c = i * 4 + wid;
    const int r = c * 8 + (lane >> 3);
    const int cs = ((lane & 7) * 16) ^ ((r & 7) << 4);
    int mrow = m0 + r; if (mrow > cnt - 1) mrow = cnt - 1;
    if (PHASE == 1) {
      const int tok = toklist[(e << 13) + mrow];
      asrc[i] = (const char*)A + (size_t)tok * (DDIM * 2) + kbase + cs;
    } else {
      asrc[i] = (const char*)A + (size_t)(off + mrow) * KB + kbase + cs;
    }
    bsrc[i] = (const char*)Bt + (size_t)e * NN * KB + (size_t)(n0 + r) * KB + kbase + cs;
    adst[i] = c * 1024;
    bdst[i] = 16384 + c * 1024;
  }
  const unsigned lofs = (unsigned)lane * 16;

  f32x4 acc[4][4] = {};

  const int wr = wid >> 1, wc = wid & 1;
  const int lr = lane & 15, lk = lane >> 4;

  // prologue: stage K-tile 0 via registers
  uint4 ar[4], br[4];
#pragma unroll
  for (int i = 0; i < 4; ++i) { ar[i] = *(const uint4*)(asrc[i]); br[i] = *(const uint4*)(bsrc[i]); }
#pragma unroll
  for (int i = 0; i < 4; ++i) {
    *(uint4*)(smem + adst[i] + lofs) = ar[i];
    *(uint4*)(smem + bdst[i] + lofs) = br[i];
  }
  __syncthreads();

  for (int t = 0; t < NT; ++t) {
    // issue next tile's global loads NOW — they fly under this tile's MFMAs
    if (t + 1 < NT) {
      const int kb = (t + 1) * 128;
#pragma unroll
      for (int i = 0; i < 4; ++i) {
        ar[i] = *(const uint4*)(asrc[i] + kb);
        br[i] = *(const uint4*)(bsrc[i] + kb);
      }
    }
#pragma unroll
    for (int kk = 0; kk < 2; ++kk) {
      bf16x8 af[4], bv[4];
#pragma unroll
      for (int mi = 0; mi < 4; ++mi) {
        const int r = wr * 64 + mi * 16 + lr;
        const int byteo = r * 128 + ((kk * 64 + lk * 16) ^ ((r & 7) << 4));
        af[mi] = *(const bf16x8*)(smem + byteo);
      }
#pragma unroll
      for (int ni = 0; ni < 4; ++ni) {
        const int r = wc * 64 + ni * 16 + lr;
        const int byteo = 16384 + r * 128 + ((kk * 64 + lk * 16) ^ ((r & 7) << 4));
        bv[ni] = *(const bf16x8*)(smem + byteo);
      }
#pragma unroll
      for (int mi = 0; mi < 4; ++mi)
#pragma unroll
        for (int ni = 0; ni < 4; ++ni)
          acc[mi][ni] = __builtin_amdgcn_mfma_f32_16x16x32_bf16(af[mi], bv[ni], acc[mi][ni], 0, 0, 0);
    }
    if (t + 1 < NT) {
      __syncthreads();  // all waves done ds_reading tile t
#pragma unroll
      for (int i = 0; i < 4; ++i) {  // vmcnt wait happens here, mostly covered by MFMAs
        *(uint4*)(smem + adst[i] + lofs) = ar[i];
        *(uint4*)(smem + bdst[i] + lofs) = br[i];
      }
      __syncthreads();  // tile t+1 visible
    }
  }

  // epilogue: C/D layout col = lane&15, row = (lane>>4)*4 + reg
  const int lq = lane >> 4;
  if (PHASE == 1) {
#pragma unroll
    for (int mi = 0; mi < 4; ++mi) {
#pragma unroll
      for (int ni = 0; ni < 4; ++ni) {
        const int n = n0 + wc * 64 + ni * 16 + lr;
        const float bv_ = bias[e * NN + n];
#pragma unroll
        for (int r2 = 0; r2 < 4; ++r2) {
          const int m = m0 + wr * 64 + mi * 16 + lq * 4 + r2;
          if (m < cnt) {
            const float xv = acc[mi][ni][r2] + bv_;
            const float g = 0.5f * xv * (1.0f + erff(xv * 0.70710678118f));
            Hout[(size_t)(off + m) * HDIM + n] = f2bf(g);
          }
        }
      }
    }
  } else {
#pragma unroll
    for (int mi = 0; mi < 4; ++mi) {
#pragma unroll
      for (int r2 = 0; r2 < 4; ++r2) {
        const int m = m0 + wr * 64 + mi * 16 + lq * 4 + r2;
        if (m < cnt) {
          const int tok = toklist[(e << 13) + m];
          const float g = gates[(e << 13) + m];
#pragma unroll
          for (int ni = 0; ni < 4; ++ni) {
            const int n = n0 + wc * 64 + ni * 16 + lr;
            // bias added once, by the s==0 split only
            const float y = acc[mi][ni][r2] + (s == 0 ? bias[e * NN + n] : 0.0f);
            atomicAdd(Out + (size_t)tok * DDIM + n, g * y);
          }
        }
      }
    }
  }
}

extern "C" void kernel_launch(void* const* d_in, const int* in_sizes, int n_in,
                              void* d_out, int out_size, void* d_ws, size_t ws_size,
                              hipStream_t stream) {
  (void)in_sizes; (void)n_in; (void)out_size; (void)ws_size;
  const float* x  = (const float*)d_in[0];
  const float* rw = (const float*)d_in[1];
  const float* rb = (const float*)d_in[2];
  const float* w1 = (const float*)d_in[3];
  const float* b1 = (const float*)d_in[4];
  const float* w2 = (const float*)d_in[5];
  const float* b2 = (const float*)d_in[6];
  float* out = (float*)d_out;
  float* logits = out + (size_t)TTOK * DDIM;

  char* ws = (char*)d_ws;
  // workspace layout (bytes), total ~109.6 MB
  unsigned short* xb  = (unsigned short*)(ws + 0);          //  8,388,608
  unsigned short* w1t = (unsigned short*)(ws + 8388608);    // 16,777,216  [E][H][D] bf16
  unsigned short* w2t = (unsigned short*)(ws + 25165824);   // 16,777,216  [E][D][H] bf16
  unsigned short* h   = (unsigned short*)(ws + 41943040);   // 67,108,864  [16384][H] bf16
  int*   toklist = (int*)(ws + 109051904);                  //    262,144
  float* gates   = (float*)(ws + 109314048);                //    262,144
  int*   counts  = (int*)(ws + 109576192);                  //         32
  int*   offsets = (int*)(ws + 109576224);                  //         32
  // router scratch ALIASED into the h region: consumed by k_scatter strictly
  // before k_gemm<1> writes h (stream-ordered), so no extra footprint.
  char* rsc = ws + 41943040;
  short*          texp      = (short*)(rsc + 0);            //  32,768
  unsigned short* tpos      = (unsigned short*)(rsc + 32768); // 32,768
  float*          tgate     = (float*)(rsc + 65536);        //  65,536
  int*            blockcnt  = (int*)(rsc + 131072);         //   8,192
  int*            blockbase = (int*)(rsc + 139264);         //   8,192

  hipMemsetAsync(out, 0, (size_t)TTOK * DDIM * sizeof(float), stream);

  k_router<<<RBLK, 256, 0, stream>>>(x, rw, rb, logits, xb, texp, tpos, tgate, blockcnt);
  k_transpose2<<<16384, dim3(32, 8), 0, stream>>>(w1, w2, w1t, w2t);
  k_offsets<<<1, 64, 0, stream>>>(blockcnt, blockbase, counts, offsets);
  k_scatter<<<TTOK / 256, 256, 0, stream>>>(texp, tpos, tgate, blockbase, toklist, gates);

  // 1D grids: expert in low 3 bits (expert -> XCD affinity)
  k_gemm<1><<<(HDIM / 128) * (TTOK / 128) * NEXP, 256, 0, stream>>>(
      xb, w1t, b1, counts, offsets, toklist, gates, h, nullptr);
  k_gemm<2><<<(DDIM / 128) * (TTOK / 128) * NEXP * 2, 256, 0, stream>>>(
      h, w2t, b2, counts, offsets, toklist, gates, nullptr, out);
}

// Round 9
// 277.293 us; speedup vs baseline: 2.0044x; 2.0044x over previous
//
#include <hip/hip_runtime.h>
#include <hip/hip_bf16.h>

#define TTOK 8192
#define DDIM 512
#define HDIM 2048
#define NEXP 8
#define RBLK 256                 // router blocks
#define RTOK (TTOK / RBLK)       // 32 tokens per router block

typedef __bf16 bf16x8 __attribute__((ext_vector_type(8)));
typedef float f32x4 __attribute__((ext_vector_type(4)));
typedef unsigned short us8 __attribute__((ext_vector_type(8)));

__device__ __forceinline__ unsigned short f2bf(float f) {
  unsigned int u = __builtin_bit_cast(unsigned int, f);
  u += 0x7fffu + ((u >> 16) & 1u);
  return (unsigned short)(u >> 16);
}

__device__ __forceinline__ void gll16(const void* g, void* l) {
  __builtin_amdgcn_global_load_lds(
      (__attribute__((address_space(1))) void*)g,
      (__attribute__((address_space(3))) void*)l, 16, 0, 0);
}

// ---------------- router: logits, top-2, gates, per-block positions; fused x->bf16 ----------------
__global__ __launch_bounds__(256) void k_router(
    const float* __restrict__ x, const float* __restrict__ rw,
    const float* __restrict__ rb, float* __restrict__ logits,
    unsigned short* __restrict__ xb,
    short* __restrict__ texp, unsigned short* __restrict__ tpos,
    float* __restrict__ tgate, int* __restrict__ blockcnt) {
  __shared__ int lcnt[NEXP];
  const int tid = threadIdx.x, wid = tid >> 6, lane = tid & 63;
  if (tid < NEXP) lcnt[tid] = 0;
  __syncthreads();
  // hoist router weights: lane covers floats [lane*8, lane*8+8)
  float4 w0[NEXP], w1[NEXP];
  float rbv[NEXP];
#pragma unroll
  for (int e = 0; e < NEXP; ++e) {
    const float4* wp = (const float4*)(rw + e * DDIM);
    w0[e] = wp[lane * 2];
    w1[e] = wp[lane * 2 + 1];
    rbv[e] = rb[e];
  }
  const int tbase = blockIdx.x * RTOK;
  for (int it = 0; it < RTOK / 4; ++it) {
    const int t = tbase + it * 4 + wid;
    const float4* xr = (const float4*)(x + (size_t)t * DDIM);
    float4 v0 = xr[lane * 2], v1 = xr[lane * 2 + 1];
    // fused bf16 conversion (replaces a separate k_cvt_x pass)
    us8 o;
    o[0] = f2bf(v0.x); o[1] = f2bf(v0.y); o[2] = f2bf(v0.z); o[3] = f2bf(v0.w);
    o[4] = f2bf(v1.x); o[5] = f2bf(v1.y); o[6] = f2bf(v1.z); o[7] = f2bf(v1.w);
    *(us8*)(xb + (size_t)t * DDIM + lane * 8) = o;
    float a[NEXP];
#pragma unroll
    for (int e = 0; e < NEXP; ++e)
      a[e] = v0.x * w0[e].x + v0.y * w0[e].y + v0.z * w0[e].z + v0.w * w0[e].w +
             v1.x * w1[e].x + v1.y * w1[e].y + v1.z * w1[e].z + v1.w * w1[e].w;
#pragma unroll
    for (int off = 32; off > 0; off >>= 1)
#pragma unroll
      for (int e = 0; e < NEXP; ++e) a[e] += __shfl_xor(a[e], off, 64);
    if (lane == 0) {
      float lg[NEXP];
#pragma unroll
      for (int e = 0; e < NEXP; ++e) lg[e] = a[e] + rbv[e];
      float4 s0, s1;
      s0.x = lg[0]; s0.y = lg[1]; s0.z = lg[2]; s0.w = lg[3];
      s1.x = lg[4]; s1.y = lg[5]; s1.z = lg[6]; s1.w = lg[7];
      ((float4*)(logits + t * NEXP))[0] = s0;
      ((float4*)(logits + t * NEXP))[1] = s1;
      int i0 = 0; float m0 = lg[0];
#pragma unroll
      for (int e = 1; e < NEXP; ++e) if (lg[e] > m0) { m0 = lg[e]; i0 = e; }
      int i1 = 0; float m1 = -3.4e38f;
#pragma unroll
      for (int e = 0; e < NEXP; ++e) if (e != i0 && lg[e] > m1) { m1 = lg[e]; i1 = e; }
      float e1 = expf(m1 - m0);
      float inv = 1.0f / (1.0f + e1);
      int p0 = atomicAdd(&lcnt[i0], 1);  // LDS atomic: block-local, cheap
      int p1 = atomicAdd(&lcnt[i1], 1);
      texp[t * 2] = (short)i0;     tpos[t * 2] = (unsigned short)p0;     tgate[t * 2] = inv;
      texp[t * 2 + 1] = (short)i1; tpos[t * 2 + 1] = (unsigned short)p1; tgate[t * 2 + 1] = e1 * inv;
    }
  }
  __syncthreads();
  if (tid < NEXP) blockcnt[blockIdx.x * NEXP + tid] = lcnt[tid];
}

// ---------------- per-block bases + expert counts/offsets (one wave) ----------------
__global__ void k_offsets(const int* __restrict__ blockcnt, int* __restrict__ blockbase,
                          int* __restrict__ counts, int* __restrict__ offsets) {
  const int e = threadIdx.x;
  if (e < NEXP) {
    int run = 0;
#pragma unroll 8
    for (int b = 0; b < RBLK; ++b) {
      blockbase[b * NEXP + e] = run;
      run += blockcnt[b * NEXP + e];
    }
    counts[e] = run;
  }
  __syncthreads();
  if (e == 0) {
    int s = 0;
    for (int q = 0; q < NEXP; ++q) { offsets[q] = s; s += counts[q]; }
  }
}

// ---------------- scatter: packed token lists + per-token combine indices ----------------
// toklist: per-expert segments (stride TTOK), position = blockbase+tpos.
// cidx[t*2+k] = GLOBAL packed row (offsets[e]+pos) for k_combine; cgate = gate.
__global__ void k_scatter(const short* __restrict__ texp, const unsigned short* __restrict__ tpos,
                          const float* __restrict__ tgate, const int* __restrict__ blockbase,
                          const int* __restrict__ offsets,
                          int* __restrict__ toklist, int* __restrict__ cidx,
                          float* __restrict__ cgate) {
  const int t = blockIdx.x * 256 + threadIdx.x;
  const int b = t / RTOK;
#pragma unroll
  for (int k = 0; k < 2; ++k) {
    const int e = (int)texp[t * 2 + k];
    const int pos = blockbase[b * NEXP + e] + (int)tpos[t * 2 + k];
    toklist[e * TTOK + pos] = t;
    cidx[t * 2 + k] = offsets[e] + pos;
    cgate[t * 2 + k] = tgate[t * 2 + k];
  }
}

// ---------------- fused weight transpose: w1 [E][D][H]->[E][H][D], w2 [E][H][D]->[E][D][H] ----------------
__global__ void k_transpose2(const float* __restrict__ w1, const float* __restrict__ w2,
                             unsigned short* __restrict__ w1t, unsigned short* __restrict__ w2t) {
  __shared__ float tile[32][33];
  const int id = blockIdx.x;
  const float* in; unsigned short* out; int R, C, rem;
  if (id < 8192) {  // w1: R=DDIM rows, C=HDIM cols
    const int e = id >> 10; rem = id & 1023;
    R = DDIM; C = HDIM;
    in = w1 + (size_t)e * R * C; out = w1t + (size_t)e * R * C;
  } else {          // w2: R=HDIM, C=DDIM
    const int e = (id - 8192) >> 10; rem = (id - 8192) & 1023;
    R = HDIM; C = DDIM;
    in = w2 + (size_t)e * R * C; out = w2t + (size_t)e * R * C;
  }
  const int ctiles = C >> 5;
  const int c0 = (rem % ctiles) * 32, r0 = (rem / ctiles) * 32;
  const int tx = threadIdx.x, ty = threadIdx.y;
#pragma unroll
  for (int i = 0; i < 32; i += 8)
    tile[ty + i][tx] = in[(size_t)(r0 + ty + i) * C + (c0 + tx)];
  __syncthreads();
#pragma unroll
  for (int i = 0; i < 32; i += 8)
    out[(size_t)(c0 + ty + i) * R + (r0 + tx)] = f2bf(tile[tx][ty + i]);
}

// ---------------- grouped GEMM, gll16 single-buffer (r5 structure, proven) ----------------
// PHASE1: xb@w1 -> gelu -> h[off+m]  (BM=128, 32KB LDS)
// PHASE2: h@w2 + b2 -> y[off+m] bf16 (BM=64, 24KB LDS, NO atomics, no split-K)
// 1D grid, expert in low 3 bits (round-robin wg->XCD => expert->XCD L2 affinity).
template <int PHASE>
__global__ __launch_bounds__(256, 2) void k_gemm(
    const unsigned short* __restrict__ A, const unsigned short* __restrict__ Bt,
    const float* __restrict__ bias, const int* __restrict__ counts,
    const int* __restrict__ offsets, const int* __restrict__ toklist,
    unsigned short* __restrict__ Out) {
  constexpr int K = (PHASE == 1) ? DDIM : HDIM;   // reduction dim
  constexpr int NN = (PHASE == 1) ? HDIM : DDIM;  // output cols
  constexpr int KB = K * 2;                       // row bytes of A/Bt
  constexpr int NX = NN / 128;                    // n-tiles
  constexpr int NXSH = (PHASE == 1) ? 4 : 2;      // log2(NX)
  constexpr int BM = (PHASE == 1) ? 128 : 64;     // m-tile
  constexpr int AI = BM / 32;                     // per-thread A staging iters (4 / 2)
  constexpr int MI = BM / 32;                     // m fragments per wave (4 / 2)
  constexpr int WRM = BM / 2;                     // rows per wave-row
  constexpr int ASZ = BM * 128;                   // A tile bytes (16K / 8K)
  constexpr int NT = K / 64;                      // K-steps

  const int id = blockIdx.x;
  const int e = id & 7;
  const int p = id >> 3;
  const int cnt = counts[e];
  const int m0 = (p >> NXSH) * BM;
  if (m0 >= cnt) return;
  const int n0 = (p & (NX - 1)) * 128;
  const int off = offsets[e];

  __shared__ alignas(16) unsigned char smem[ASZ + 16384];

  const int tid = threadIdx.x;
  const int wid = tid >> 6, lane = tid & 63;

  // staging: 1KB chunks; chunk c covers rows [c*8, c*8+8), 128B/row.
  // LDS dest linear (global_load_lds); source byte-in-row pre-XOR-swizzled so the
  // swizzled ds_read below sees the right data (both-sides involution).
  const char* asrc[AI];
  const char* bsrc[4];
  unsigned adst[AI], bdst[4];
#pragma unroll
  for (int i = 0; i < AI; ++i) {
    const int c = i * 4 + wid;
    const int r = c * 8 + (lane >> 3);
    const int cs = ((lane & 7) * 16) ^ ((r & 7) << 4);
    int mrow = m0 + r; if (mrow > cnt - 1) mrow = cnt - 1;
    if (PHASE == 1) {
      const int tok = toklist[(e << 13) + mrow];
      asrc[i] = (const char*)A + (size_t)tok * (DDIM * 2) + cs;
    } else {
      asrc[i] = (const char*)A + (size_t)(off + mrow) * KB + cs;
    }
    adst[i] = c * 1024;
  }
#pragma unroll
  for (int i = 0; i < 4; ++i) {
    const int c = i * 4 + wid;
    const int r = c * 8 + (lane >> 3);
    const int cs = ((lane & 7) * 16) ^ ((r & 7) << 4);
    bsrc[i] = (const char*)Bt + (size_t)e * NN * KB + (size_t)(n0 + r) * KB + cs;
    bdst[i] = ASZ + c * 1024;
  }

  f32x4 acc[MI][4] = {};

  const int wr = wid >> 1, wc = wid & 1;
  const int lr = lane & 15, lk = lane >> 4;

  for (int t = 0; t < NT; ++t) {
    const int kb = t * 128;
#pragma unroll
    for (int i = 0; i < AI; ++i) gll16(asrc[i] + kb, smem + adst[i]);
#pragma unroll
    for (int i = 0; i < 4; ++i) gll16(bsrc[i] + kb, smem + bdst[i]);
    __syncthreads();
#pragma unroll
    for (int kk = 0; kk < 2; ++kk) {
      bf16x8 af[MI], bv[4];
#pragma unroll
      for (int mi = 0; mi < MI; ++mi) {
        const int r = wr * WRM + mi * 16 + lr;
        const int byteo = r * 128 + ((kk * 64 + lk * 16) ^ ((r & 7) << 4));
        af[mi] = *(const bf16x8*)(smem + byteo);
      }
#pragma unroll
      for (int ni = 0; ni < 4; ++ni) {
        const int r = wc * 64 + ni * 16 + lr;
        const int byteo = ASZ + r * 128 + ((kk * 64 + lk * 16) ^ ((r & 7) << 4));
        bv[ni] = *(const bf16x8*)(smem + byteo);
      }
#pragma unroll
      for (int mi = 0; mi < MI; ++mi)
#pragma unroll
        for (int ni = 0; ni < 4; ++ni)
          acc[mi][ni] = __builtin_amdgcn_mfma_f32_16x16x32_bf16(af[mi], bv[ni], acc[mi][ni], 0, 0, 0);
    }
    if (t + 1 < NT) __syncthreads();
  }

  // epilogue: C/D layout col = lane&15, row = (lane>>4)*4 + reg
  const int lq = lane >> 4;
#pragma unroll
  for (int mi = 0; mi < MI; ++mi) {
#pragma unroll
    for (int ni = 0; ni < 4; ++ni) {
      const int n = n0 + wc * 64 + ni * 16 + lr;
      const float bv_ = bias[e * NN + n];
#pragma unroll
      for (int r2 = 0; r2 < 4; ++r2) {
        const int m = m0 + wr * WRM + mi * 16 + lq * 4 + r2;
        if (m < cnt) {
          if (PHASE == 1) {
            const float xv = acc[mi][ni][r2] + bv_;
            const float g = 0.5f * xv * (1.0f + erff(xv * 0.70710678118f));
            Out[(size_t)(off + m) * HDIM + n] = f2bf(g);
          } else {
            Out[(size_t)(off + m) * DDIM + n] = f2bf(acc[mi][ni][r2] + bv_);
          }
        }
      }
    }
  }
}

// ---------------- combine: out[t] = g0*y[idx0] + g1*y[idx1]  (coalesced, no atomics) ----------------
__global__ __launch_bounds__(256) void k_combine(const unsigned short* __restrict__ yp,
                                                 const int* __restrict__ cidx,
                                                 const float* __restrict__ cgate,
                                                 float* __restrict__ out) {
  const int t = blockIdx.x * 4 + (threadIdx.x >> 6);
  const int lane = threadIdx.x & 63;
  const int i0 = cidx[t * 2], i1 = cidx[t * 2 + 1];
  const float g0 = cgate[t * 2], g1 = cgate[t * 2 + 1];
  us8 a = *(const us8*)(yp + (size_t)i0 * DDIM + lane * 8);
  us8 b = *(const us8*)(yp + (size_t)i1 * DDIM + lane * 8);
  float o[8];
#pragma unroll
  for (int j = 0; j < 8; ++j) {
    const float va = __builtin_bit_cast(float, (unsigned)a[j] << 16);
    const float vb = __builtin_bit_cast(float, (unsigned)b[j] << 16);
    o[j] = g0 * va + g1 * vb;
  }
  float* op = out + (size_t)t * DDIM + lane * 8;
  *(float4*)op = *(float4*)o;
  *(float4*)(op + 4) = *(float4*)(o + 4);
}

extern "C" void kernel_launch(void* const* d_in, const int* in_sizes, int n_in,
                              void* d_out, int out_size, void* d_ws, size_t ws_size,
                              hipStream_t stream) {
  (void)in_sizes; (void)n_in; (void)out_size; (void)ws_size;
  const float* x  = (const float*)d_in[0];
  const float* rw = (const float*)d_in[1];
  const float* rb = (const float*)d_in[2];
  const float* w1 = (const float*)d_in[3];
  const float* b1 = (const float*)d_in[4];
  const float* w2 = (const float*)d_in[5];
  const float* b2 = (const float*)d_in[6];
  float* out = (float*)d_out;
  float* logits = out + (size_t)TTOK * DDIM;

  char* ws = (char*)d_ws;
  // workspace layout (bytes), max offset ~109.45 MB (less than r5's 109.58)
  unsigned short* xb  = (unsigned short*)(ws + 0);          //  8,388,608
  unsigned short* w1t = (unsigned short*)(ws + 8388608);    // 16,777,216  [E][H][D] bf16
  unsigned short* w2t = (unsigned short*)(ws + 25165824);   // 16,777,216  [E][D][H] bf16
  unsigned short* h   = (unsigned short*)(ws + 41943040);   // 67,108,864  [16384][H] bf16
  int*   toklist = (int*)(ws + 109051904);                  //    262,144
  int*   cidx    = (int*)(ws + 109314048);                  //     65,536
  float* cgate   = (float*)(ws + 109379584);                //     65,536
  int*   counts  = (int*)(ws + 109445120);                  //         32
  int*   offsets = (int*)(ws + 109445152);                  //         32
  // y_packed [16384][512] bf16 ALIASES w1t (dead after k_gemm<1>, stream-ordered).
  unsigned short* yp = w1t;
  // router scratch ALIASED into the h region: consumed by k_scatter strictly
  // before k_gemm<1> writes h (stream-ordered), so no extra footprint.
  char* rsc = ws + 41943040;
  short*          texp      = (short*)(rsc + 0);            //  32,768
  unsigned short* tpos      = (unsigned short*)(rsc + 32768); // 32,768
  float*          tgate     = (float*)(rsc + 65536);        //  65,536
  int*            blockcnt  = (int*)(rsc + 131072);         //   8,192
  int*            blockbase = (int*)(rsc + 139264);         //   8,192

  k_router<<<RBLK, 256, 0, stream>>>(x, rw, rb, logits, xb, texp, tpos, tgate, blockcnt);
  k_transpose2<<<16384, dim3(32, 8), 0, stream>>>(w1, w2, w1t, w2t);
  k_offsets<<<1, 64, 0, stream>>>(blockcnt, blockbase, counts, offsets);
  k_scatter<<<TTOK / 256, 256, 0, stream>>>(texp, tpos, tgate, blockbase, offsets,
                                            toklist, cidx, cgate);

  // 1D grids: expert in low 3 bits (expert -> XCD affinity)
  k_gemm<1><<<(HDIM / 128) * (TTOK / 128) * NEXP, 256, 0, stream>>>(
      xb, w1t, b1, counts, offsets, toklist, h);
  k_gemm<2><<<(DDIM / 128) * (TTOK / 64) * NEXP, 256, 0, stream>>>(
      h, w2t, b2, counts, offsets, nullptr, yp);
  k_combine<<<TTOK / 4, 256, 0, stream>>>(yp, cidx, cgate, out);
}